// Round 2
// baseline (1829.775 us; speedup 1.0000x reference)
//
#include <hip/hip_runtime.h>
#include <cmath>

// Problem constants
constexpr int kN = 8;
constexpr int kC = 32;
constexpr int kH = 256;
constexpr int kW = 256;
constexpr int kHW = kH * kW;     // 65536
constexpr int kWF = 129;         // W/2+1
constexpr int kHWF = kH * kWF;   // 33024
constexpr float kPI = 3.14159265358979323846f;

__device__ __forceinline__ float sigmoidf_(float x) { return 1.f / (1.f + expf(-x)); }

// ---------------------------------------------------------------------------
// K1: LayerNorm over C (=32) + 1x1 conv (32->32) + ReLU.  Optionally a second
// weight set producing a second output (event branch feeds two 1x1 convs).
// One thread per pixel; weights in LDS.
// ---------------------------------------------------------------------------
template <bool TWO>
__global__ __launch_bounds__(256) void lnmv_kernel(
    const float* __restrict__ in,
    const float* __restrict__ lng, const float* __restrict__ lnb,
    const float* __restrict__ w1, const float* __restrict__ b1, float* __restrict__ out1,
    const float* __restrict__ w2, const float* __restrict__ b2, float* __restrict__ out2)
{
    __shared__ __align__(16) float wl1[1024];
    __shared__ __align__(16) float wl2[TWO ? 1024 : 4];
    __shared__ float bl1[32], bl2[32], gl[32], bbl[32];
    int tid = threadIdx.x;
    for (int e = tid; e < 1024; e += 256) {
        wl1[e] = w1[e];
        if (TWO) wl2[e] = w2[e];
    }
    if (tid < 32) {
        bl1[tid] = b1[tid]; gl[tid] = lng[tid]; bbl[tid] = lnb[tid];
        if (TWO) bl2[tid] = b2[tid];
    }
    __syncthreads();

    int p = blockIdx.x * 256 + tid;         // < N*HW = 524288 exactly
    int n = p >> 16;                        // /kHW
    int rem = p & 65535;
    const float* base = in + (size_t)n * kC * kHW + rem;

    float v[32];
    float mu = 0.f;
#pragma unroll
    for (int c = 0; c < 32; ++c) { v[c] = base[(size_t)c * kHW]; mu += v[c]; }
    mu *= 0.03125f;
    float var = 0.f;
#pragma unroll
    for (int c = 0; c < 32; ++c) { float d = v[c] - mu; var += d * d; }
    var *= 0.03125f;
    float rs = rsqrtf(var + 1e-5f);
#pragma unroll
    for (int c = 0; c < 32; ++c) v[c] = (v[c] - mu) * rs * gl[c] + bbl[c];

    {
        float* o = out1 + (size_t)n * kC * kHW + rem;
#pragma unroll
        for (int oc = 0; oc < 32; ++oc) {
            const float4* wr = reinterpret_cast<const float4*>(wl1 + oc * 32);
            float acc = bl1[oc];
#pragma unroll
            for (int q = 0; q < 8; ++q) {
                float4 wv = wr[q];
                acc += wv.x * v[4*q] + wv.y * v[4*q+1] + wv.z * v[4*q+2] + wv.w * v[4*q+3];
            }
            o[(size_t)oc * kHW] = fmaxf(acc, 0.f);
        }
    }
    if (TWO) {
        float* o = out2 + (size_t)n * kC * kHW + rem;
#pragma unroll
        for (int oc = 0; oc < 32; ++oc) {
            const float4* wr = reinterpret_cast<const float4*>(wl2 + oc * 32);
            float acc = bl2[oc];
#pragma unroll
            for (int q = 0; q < 8; ++q) {
                float4 wv = wr[q];
                acc += wv.x * v[4*q] + wv.y * v[4*q+1] + wv.z * v[4*q+2] + wv.w * v[4*q+3];
            }
            o[(size_t)oc * kHW] = fmaxf(acc, 0.f);
        }
    }
}

// ---------------------------------------------------------------------------
// K2: generic depthwise 3x3, pad 1, with bias. Runtime CH/H/W.
// ---------------------------------------------------------------------------
__global__ __launch_bounds__(256) void dw3x3_kernel(
    const float* __restrict__ in, const float* __restrict__ w,
    const float* __restrict__ bias, float* __restrict__ out,
    int CH, int Hd, int Wd, int total)
{
    int idx = blockIdx.x * 256 + threadIdx.x;
    if (idx >= total) return;
    int wx = idx % Wd;
    int rest = idx / Wd;
    int hy = rest % Hd;
    int pl = rest / Hd;          // n*CH + ch
    int ch = pl % CH;

    const float* ip = in + (size_t)pl * Hd * Wd;
    const float* wp = w + ch * 9;
    float acc = bias[ch];
#pragma unroll
    for (int dy = -1; dy <= 1; ++dy) {
        int yy = hy + dy;
        if (yy < 0 || yy >= Hd) continue;
        const float* rp = ip + (size_t)yy * Wd;
#pragma unroll
        for (int dx = -1; dx <= 1; ++dx) {
            int xx = wx + dx;
            if (xx < 0 || xx >= Wd) continue;
            acc += rp[xx] * wp[(dy + 1) * 3 + (dx + 1)];
        }
    }
    out[idx] = acc;
}

// ---------------------------------------------------------------------------
// K3: full 3x3 conv 32 -> COUT (pad 1) on (N,32,256,256). Block = 4 rows,
// each of 64 lanes; each thread computes 4 pixels (w, w+64, w+128, w+192).
// ACT: 0 none, 2 sigmoid.
// ---------------------------------------------------------------------------
template <int COUT, int COUTP, int ACT>
__global__ __launch_bounds__(256) void conv3x3_kernel(
    const float* __restrict__ in, const float* __restrict__ wg,
    const float* __restrict__ bias, float* __restrict__ out)
{
    __shared__ __align__(16) float wl[288 * COUTP];
    __shared__ float bl[COUT];
    int tid = threadIdx.x;
    for (int e = tid; e < 288 * COUTP; e += 256) {
        int oc = e % COUTP;
        int t = e / COUTP;                 // ic*9 + tap
        wl[e] = (oc < COUT) ? wg[(oc * 32 + (t / 9)) * 9 + (t % 9)] : 0.f;
    }
    if (tid < COUT) bl[tid] = bias[tid];
    __syncthreads();

    int row = blockIdx.x * 4 + (tid >> 6);   // < N*H = 2048
    int lane = tid & 63;
    int n = row >> 8;
    int h = row & 255;

    float acc[4][COUTP];
#pragma unroll
    for (int px = 0; px < 4; ++px)
#pragma unroll
        for (int oc = 0; oc < COUTP; ++oc) acc[px][oc] = (oc < COUT) ? bl[oc] : 0.f;

    const float* ib = in + (size_t)n * 32 * kHW;
    for (int ic = 0; ic < 32; ++ic) {
        const float* ipl = ib + (size_t)ic * kHW;
#pragma unroll
        for (int ky = 0; ky < 3; ++ky) {
            int yy = h + ky - 1;
            if (yy < 0 || yy > 255) continue;
            const float* rp = ipl + (size_t)yy * 256;
#pragma unroll
            for (int kx = 0; kx < 3; ++kx) {
                float val[4];
#pragma unroll
                for (int px = 0; px < 4; ++px) {
                    int xx = lane + px * 64 + kx - 1;
                    val[px] = (xx >= 0 && xx < 256) ? rp[xx] : 0.f;
                }
                const float4* wr = reinterpret_cast<const float4*>(wl + (ic * 9 + ky * 3 + kx) * COUTP);
#pragma unroll
                for (int q = 0; q < COUTP / 4; ++q) {
                    float4 wv = wr[q];
#pragma unroll
                    for (int px = 0; px < 4; ++px) {
                        acc[px][4*q+0] += val[px] * wv.x;
                        acc[px][4*q+1] += val[px] * wv.y;
                        acc[px][4*q+2] += val[px] * wv.z;
                        acc[px][4*q+3] += val[px] * wv.w;
                    }
                }
            }
        }
    }

    float* ob = out + (size_t)n * COUT * kHW + (size_t)h * 256;
#pragma unroll
    for (int oc = 0; oc < COUT; ++oc) {
#pragma unroll
        for (int px = 0; px < 4; ++px) {
            float r = acc[px][oc];
            if (ACT == 2) r = sigmoidf_(r);
            ob[(size_t)oc * kHW + lane + px * 64] = r;
        }
    }
}

// ---------------------------------------------------------------------------
// K4: modulated deformable conv 3x3 (torchvision semantics per reference).
// Block = 4 rows x 64 lanes, 4 pixels/thread. Weights (9*32*32) in LDS.
// ---------------------------------------------------------------------------
__global__ __launch_bounds__(256) void deform_kernel(
    const float* __restrict__ x, const float* __restrict__ off,
    const float* __restrict__ msk, const float* __restrict__ wt,
    float* __restrict__ out)
{
    __shared__ __align__(16) float wl[9 * 32 * 32];
    int tid = threadIdx.x;
    for (int e = tid; e < 9216; e += 256) {
        int o = e & 31;
        int t = e >> 5;
        int c = t & 31;
        int k = t >> 5;
        wl[e] = wt[((size_t)(o * 32 + c)) * 9 + k];
    }
    __syncthreads();

    int row = blockIdx.x * 4 + (tid >> 6);
    int lane = tid & 63;
    int n = row >> 8;
    int h = row & 255;
    int pixbase = h * 256 + lane;

    const float* offb = off + (size_t)n * 18 * kHW + pixbase;
    const float* mskb = msk + (size_t)n * 9 * kHW + pixbase;
    const float* xb = x + (size_t)n * 32 * kHW;

    float acc[4][32];
#pragma unroll
    for (int px = 0; px < 4; ++px)
#pragma unroll
        for (int oc = 0; oc < 32; ++oc) acc[px][oc] = 0.f;

    for (int k = 0; k < 9; ++k) {
        int ki = k / 3 - 1, kj = k % 3 - 1;
        int i00[4], i01[4], i10[4], i11[4];
        float w00[4], w01[4], w10[4], w11[4];
#pragma unroll
        for (int px = 0; px < 4; ++px) {
            int wx = lane + px * 64;
            float oy = offb[(size_t)(2 * k) * kHW + px * 64];
            float ox = offb[(size_t)(2 * k + 1) * kHW + px * 64];
            float m = mskb[(size_t)k * kHW + px * 64];
            float py = (float)(h + ki) + oy;
            float pxx = (float)(wx + kj) + ox;
            float y0f = floorf(py), x0f = floorf(pxx);
            float fy = py - y0f, fx = pxx - x0f;
            float vy0 = (y0f >= 0.f && y0f <= 255.f) ? 1.f : 0.f;
            float vy1 = (y0f >= -1.f && y0f <= 254.f) ? 1.f : 0.f;
            float vx0 = (x0f >= 0.f && x0f <= 255.f) ? 1.f : 0.f;
            float vx1 = (x0f >= -1.f && x0f <= 254.f) ? 1.f : 0.f;
            int y0 = min(max((int)y0f, 0), 255);
            int y1 = min(max((int)y0f + 1, 0), 255);
            int x0 = min(max((int)x0f, 0), 255);
            int x1 = min(max((int)x0f + 1, 0), 255);
            i00[px] = y0 * 256 + x0; i01[px] = y0 * 256 + x1;
            i10[px] = y1 * 256 + x0; i11[px] = y1 * 256 + x1;
            w00[px] = (1.f - fy) * (1.f - fx) * m * vy0 * vx0;
            w01[px] = (1.f - fy) * fx * m * vy0 * vx1;
            w10[px] = fy * (1.f - fx) * m * vy1 * vx0;
            w11[px] = fy * fx * m * vy1 * vx1;
        }
        for (int c = 0; c < 32; ++c) {
            const float* xp = xb + (size_t)c * kHW;
            float s[4];
#pragma unroll
            for (int px = 0; px < 4; ++px) {
                s[px] = w00[px] * xp[i00[px]] + w01[px] * xp[i01[px]] +
                        w10[px] * xp[i10[px]] + w11[px] * xp[i11[px]];
            }
            const float4* wr = reinterpret_cast<const float4*>(wl + (size_t)(k * 32 + c) * 32);
#pragma unroll
            for (int q = 0; q < 8; ++q) {
                float4 wv = wr[q];
#pragma unroll
                for (int px = 0; px < 4; ++px) {
                    acc[px][4*q+0] += s[px] * wv.x;
                    acc[px][4*q+1] += s[px] * wv.y;
                    acc[px][4*q+2] += s[px] * wv.z;
                    acc[px][4*q+3] += s[px] * wv.w;
                }
            }
        }
    }

    float* ob = out + (size_t)n * 32 * kHW + pixbase;
#pragma unroll
    for (int oc = 0; oc < 32; ++oc)
#pragma unroll
        for (int px = 0; px < 4; ++px)
            ob[(size_t)oc * kHW + px * 64] = acc[px][oc];
}

// ---------------------------------------------------------------------------
// FFT-256: radix-2 Stockham (DIF) in LDS, 64 lanes per FFT, 4 FFTs per block.
// tw[t] = exp(-2*pi*i*t/256), t in [0,128). sgn=+1 forward, -1 inverse.
// Result ends in A after 8 stages, natural order.
// ---------------------------------------------------------------------------
__device__ __forceinline__ void fft256_stages(float2* A, float2* Bb, const float2* tw,
                                              int lane, float sgn)
{
    float2* src = A;
    float2* dst = Bb;
#pragma unroll
    for (int s = 0; s < 8; ++s) {
        int m = 1 << s;
        __syncthreads();
#pragma unroll
        for (int r = 0; r < 2; ++r) {
            int q = lane + (r << 6);
            float2 c0 = src[q];
            float2 c1 = src[q + 128];
            float2 w = tw[q & ~(m - 1)];
            float wy = w.y * sgn;
            float sx = c0.x + c1.x, sy = c0.y + c1.y;
            float dx = c0.x - c1.x, dy = c0.y - c1.y;
            int dlo = (q & (m - 1)) + ((q & ~(m - 1)) << 1);
            float2 a; a.x = sx; a.y = sy;
            float2 b; b.x = w.x * dx - wy * dy; b.y = w.x * dy + wy * dx;
            dst[dlo] = a;
            dst[dlo + m] = b;
        }
        float2* t = src; src = dst; dst = t;
    }
    __syncthreads();
}

__device__ __forceinline__ void make_tw(float2* tw, int tid)
{
    if (tid < 128) {
        float ang = -kPI * (float)tid / 128.f;  // -2*pi*t/256
        float2 w; w.x = cosf(ang); w.y = sinf(ang);
        tw[tid] = w;
    }
}

// rows: real 256 -> 129 complex bins. 4 rows per block.
__global__ __launch_bounds__(256) void fft_rows_r2c(const float* __restrict__ in,
                                                    float2* __restrict__ out)
{
    __shared__ float2 A[4][256];
    __shared__ float2 Bb[4][256];
    __shared__ float2 tw[128];
    int tid = threadIdx.x;
    int sub = tid >> 6, lane = tid & 63;
    make_tw(tw, tid);
    size_t row = (size_t)blockIdx.x * 4 + sub;
    const float* rp = in + row * 256;
#pragma unroll
    for (int r = 0; r < 4; ++r) {
        int i = lane + 64 * r;
        float2 a; a.x = rp[i]; a.y = 0.f;
        A[sub][i] = a;
    }
    fft256_stages(A[sub], Bb[sub], tw, lane, 1.f);
    float2* op = out + row * kWF;
    op[lane] = A[sub][lane];
    op[lane + 64] = A[sub][lane + 64];
    if (lane == 0) op[128] = A[sub][128];
}

// cols: in-place complex FFT over H for 4 adjacent columns per block.
__global__ __launch_bounds__(256) void fft_cols_c2c(float2* __restrict__ buf)
{
    __shared__ float2 A[4][256];
    __shared__ float2 Bb[4][256];
    __shared__ float2 tw[128];
    int tid = threadIdx.x;
    int sub = tid >> 6, lane = tid & 63;
    make_tw(tw, tid);
    int b = blockIdx.x;
    int p = b / 33;
    int col0 = (b % 33) * 4;
    int ncols = (col0 + 4 <= kWF) ? 4 : (kWF - col0);
    float2* base = buf + (size_t)p * kHWF + col0;
    for (int e = tid; e < 1024; e += 256) {
        int cc = e & 3, hh = e >> 2;
        if (cc < ncols) A[cc][hh] = base[(size_t)hh * kWF + cc];
    }
    fft256_stages(A[sub], Bb[sub], tw, lane, 1.f);
    for (int e = tid; e < 1024; e += 256) {
        int cc = e & 3, hh = e >> 2;
        if (cc < ncols) base[(size_t)hh * kWF + cc] = A[cc][hh];
    }
}

// inverse col FFT of (xf * real_mask), out-of-place.
__global__ __launch_bounds__(256) void ifft_cols_mask(const float2* __restrict__ xf,
                                                      const float* __restrict__ spm,
                                                      float2* __restrict__ out)
{
    __shared__ float2 A[4][256];
    __shared__ float2 Bb[4][256];
    __shared__ float2 tw[128];
    int tid = threadIdx.x;
    int sub = tid >> 6, lane = tid & 63;
    make_tw(tw, tid);
    int b = blockIdx.x;
    int p = b / 33;
    int col0 = (b % 33) * 4;
    int ncols = (col0 + 4 <= kWF) ? 4 : (kWF - col0);
    const float2* xb = xf + (size_t)p * kHWF + col0;
    const float* mb = spm + (size_t)p * kHWF + col0;
    for (int e = tid; e < 1024; e += 256) {
        int cc = e & 3, hh = e >> 2;
        if (cc < ncols) {
            float2 a = xb[(size_t)hh * kWF + cc];
            float m = mb[(size_t)hh * kWF + cc];
            a.x *= m; a.y *= m;
            A[cc][hh] = a;
        }
    }
    fft256_stages(A[sub], Bb[sub], tw, lane, -1.f);
    float2* ob = out + (size_t)p * kHWF + col0;
    for (int e = tid; e < 1024; e += 256) {
        int cc = e & 3, hh = e >> 2;
        if (cc < ncols) ob[(size_t)hh * kWF + cc] = A[cc][hh];
    }
}

// rows inverse: 129 complex (Hermitian-extended) -> 256 real, scaled 1/65536.
__global__ __launch_bounds__(256) void ifft_rows_c2r(const float2* __restrict__ in,
                                                     float* __restrict__ out)
{
    __shared__ float2 A[4][256];
    __shared__ float2 Bb[4][256];
    __shared__ float2 tw[128];
    int tid = threadIdx.x;
    int sub = tid >> 6, lane = tid & 63;
    make_tw(tw, tid);
    size_t row = (size_t)blockIdx.x * 4 + sub;
    const float2* ip = in + row * kWF;
#pragma unroll
    for (int r = 0; r < 4; ++r) {
        int k = lane + 64 * r;
        if (k <= 128) {
            A[sub][k] = ip[k];
        } else {
            float2 c = ip[256 - k];
            c.y = -c.y;
            A[sub][k] = c;
        }
    }
    fft256_stages(A[sub], Bb[sub], tw, lane, -1.f);
    float* op = out + row * 256;
#pragma unroll
    for (int r = 0; r < 4; ++r) {
        int k = lane + 64 * r;
        op[k] = A[sub][k].x * (1.f / 65536.f);
    }
}

// ---------------------------------------------------------------------------
// 1x1 conv on the frequency-domain planes (plane = 33024 px). 2 pixels/thread.
// CPLX: input is float2 planes (32 of them) -> 64 channels [real; imag].
// ACT: 0 none, 1 relu, 2 sigmoid.
// ---------------------------------------------------------------------------
template <int CIN, int COUT, int ACT, bool CPLX>
__global__ __launch_bounds__(256) void conv1x1_kernel(
    const void* __restrict__ inv, const float* __restrict__ wg,
    const float* __restrict__ bias, float* __restrict__ out)
{
    constexpr int PL = kHWF;
    __shared__ __align__(16) float wl[COUT * CIN];
    __shared__ float bl[COUT];
    int tid = threadIdx.x;
    for (int e = tid; e < COUT * CIN; e += 256) wl[e] = wg[e];
    if (tid < COUT) bl[tid] = bias[tid];
    __syncthreads();

    int p0 = blockIdx.x * 512 + tid;   // grid sized so p0+256 < N*PL always
    int p1 = p0 + 256;
    int n0 = p0 / PL, r0 = p0 % PL;
    int n1 = p1 / PL, r1 = p1 % PL;

    float v0[CIN], v1[CIN];
    if (CPLX) {
        const float2* in2 = (const float2*)inv;
#pragma unroll
        for (int c = 0; c < 32; ++c) {
            float2 a = in2[(size_t)(n0 * 32 + c) * PL + r0];
            float2 b = in2[(size_t)(n1 * 32 + c) * PL + r1];
            v0[c] = a.x; v0[32 + c] = a.y;
            v1[c] = b.x; v1[32 + c] = b.y;
        }
    } else {
        const float* inf_ = (const float*)inv;
#pragma unroll
        for (int c = 0; c < CIN; ++c) {
            v0[c] = inf_[(size_t)(n0 * CIN + c) * PL + r0];
            v1[c] = inf_[(size_t)(n1 * CIN + c) * PL + r1];
        }
    }

#pragma unroll
    for (int oc = 0; oc < COUT; ++oc) {
        const float4* wr = reinterpret_cast<const float4*>(wl + oc * CIN);
        float a0 = bl[oc], a1 = bl[oc];
#pragma unroll
        for (int q = 0; q < CIN / 4; ++q) {
            float4 wv = wr[q];
            a0 += wv.x * v0[4*q] + wv.y * v0[4*q+1] + wv.z * v0[4*q+2] + wv.w * v0[4*q+3];
            a1 += wv.x * v1[4*q] + wv.y * v1[4*q+1] + wv.z * v1[4*q+2] + wv.w * v1[4*q+3];
        }
        if (ACT == 1) { a0 = fmaxf(a0, 0.f); a1 = fmaxf(a1, 0.f); }
        if (ACT == 2) { a0 = sigmoidf_(a0); a1 = sigmoidf_(a1); }
        out[(size_t)(n0 * COUT + oc) * PL + r0] = a0;
        out[(size_t)(n1 * COUT + oc) * PL + r1] = a1;
    }
}

// ---------------------------------------------------------------------------
// Final: GLU with exact gelu on channels [16..32), 1x1 conv 16->32, bias,
// + residual input_flow.
// ---------------------------------------------------------------------------
__global__ __launch_bounds__(256) void final_kernel(
    const float* __restrict__ g, const float* __restrict__ flow,
    const float* __restrict__ wg, const float* __restrict__ bias,
    float* __restrict__ out)
{
    __shared__ __align__(16) float wl[32 * 16];
    __shared__ float bl[32];
    int tid = threadIdx.x;
    for (int e = tid; e < 512; e += 256) wl[e] = wg[e];
    if (tid < 32) bl[tid] = bias[tid];
    __syncthreads();

    int p = blockIdx.x * 256 + tid;
    int n = p >> 16;
    int rem = p & 65535;
    const float* gb = g + (size_t)n * 32 * kHW + rem;

    float v[16];
#pragma unroll
    for (int c = 0; c < 16; ++c) {
        float a = gb[(size_t)c * kHW];
        float b = gb[(size_t)(16 + c) * kHW];
        float ge = 0.5f * b * (1.f + erff(b * 0.70710678118654752f));
        v[c] = a * ge;
    }

    const float* fb = flow + (size_t)n * 32 * kHW + rem;
    float* ob = out + (size_t)n * 32 * kHW + rem;
#pragma unroll
    for (int oc = 0; oc < 32; ++oc) {
        const float4* wr = reinterpret_cast<const float4*>(wl + oc * 16);
        float acc = bl[oc];
#pragma unroll
        for (int q = 0; q < 4; ++q) {
            float4 wv = wr[q];
            acc += wv.x * v[4*q] + wv.y * v[4*q+1] + wv.z * v[4*q+2] + wv.w * v[4*q+3];
        }
        ob[(size_t)oc * kHW] = acc + fb[(size_t)oc * kHW];
    }
}

// ---------------------------------------------------------------------------
// Buffer plan (3 ws slots of 16,908,288 floats = 202.9 MB total + d_out):
//   A: t1 -> offset -> xf(complex) ------------------ live 7..13
//   B: t2 -> mask -> dcf -> h2 -> spm -> x_irfft
//   C: t3 -> dc -> h1 -> h3 -> ycol -> g
//   d_out: x (steps 3..7, exactly out_size floats) -> final output
// ---------------------------------------------------------------------------
extern "C" void kernel_launch(void* const* d_in, const int* in_sizes, int n_in,
                              void* d_out, int out_size, void* d_ws, size_t ws_size,
                              hipStream_t stream)
{
    (void)in_sizes; (void)n_in; (void)out_size; (void)ws_size;

    const float* input_flow  = (const float*)d_in[0];
    const float* input_event = (const float*)d_in[1];
    const float* ln_flow_g   = (const float*)d_in[2];
    const float* ln_flow_b   = (const float*)d_in[3];
    const float* ln_event_g  = (const float*)d_in[4];
    const float* ln_event_b  = (const float*)d_in[5];
    const float* ff_w1 = (const float*)d_in[6];
    const float* ff_b1 = (const float*)d_in[7];
    const float* ff_w2 = (const float*)d_in[8];
    const float* ff_b2 = (const float*)d_in[9];
    const float* fo_w1 = (const float*)d_in[10];
    const float* fo_b1 = (const float*)d_in[11];
    const float* fo_w2 = (const float*)d_in[12];
    const float* fo_b2 = (const float*)d_in[13];
    const float* fm_w1 = (const float*)d_in[14];
    const float* fm_b1 = (const float*)d_in[15];
    const float* fm_w2 = (const float*)d_in[16];
    const float* fm_b2 = (const float*)d_in[17];
    const float* dc_weight = (const float*)d_in[18];
    const float* sf_w1 = (const float*)d_in[19];
    const float* sf_b1 = (const float*)d_in[20];
    const float* sf_w2 = (const float*)d_in[21];
    const float* sf_b2 = (const float*)d_in[22];
    const float* sf_w3 = (const float*)d_in[23];
    const float* sf_b3 = (const float*)d_in[24];
    const float* sf_w4 = (const float*)d_in[25];
    const float* sf_b4 = (const float*)d_in[26];
    const float* fl_w1 = (const float*)d_in[27];
    const float* fl_b1 = (const float*)d_in[28];
    const float* fl_w2 = (const float*)d_in[29];
    const float* fl_b2 = (const float*)d_in[30];
    float* out = (float*)d_out;

    // 3 aliased workspace slots of 16,908,288 floats (67.6 MB) each.
    const size_t S = (size_t)16908288;
    float* A = (float*)d_ws;
    float* B = A + S;
    float* Cs = B + S;
    float* X = out;   // x lives in d_out between steps 3 and 7

    // 1) t1 = relu(ff_w1 @ LN(flow))              -> A
    lnmv_kernel<false><<<2048, 256, 0, stream>>>(input_flow, ln_flow_g, ln_flow_b,
                                                 ff_w1, ff_b1, A,
                                                 nullptr, nullptr, nullptr);
    // 2) t2 = relu(fo_w1 @ LN(event)) -> B ; t3 = relu(fm_w1 @ LN(event)) -> C
    lnmv_kernel<true><<<2048, 256, 0, stream>>>(input_event, ln_event_g, ln_event_b,
                                                fo_w1, fo_b1, B,
                                                fm_w1, fm_b1, Cs);
    // 3) x = dw3x3(t1) + ff_b2                    -> X (d_out)
    dw3x3_kernel<<<65536, 256, 0, stream>>>(A, ff_w2, ff_b2, X, 32, 256, 256, 16777216);
    // 4) offset = conv3x3(t2)                     -> A
    conv3x3_kernel<18, 20, 0><<<512, 256, 0, stream>>>(B, fo_w2, fo_b2, A);
    // 5) mask = sigmoid(conv3x3(t3))              -> B
    conv3x3_kernel<9, 12, 2><<<512, 256, 0, stream>>>(Cs, fm_w2, fm_b2, B);
    // 6) dc = deform(x, offset, mask)             -> C
    deform_kernel<<<512, 256, 0, stream>>>(X, A, B, dc_weight, Cs);
    // 7) xf = rfft2(x)                            -> A (float2)
    fft_rows_r2c<<<16384, 256, 0, stream>>>(X, (float2*)A);
    fft_cols_c2c<<<8448, 256, 0, stream>>>((float2*)A);
    // 8) dcf = rfft2(dc)                          -> B (float2)
    fft_rows_r2c<<<16384, 256, 0, stream>>>(Cs, (float2*)B);
    fft_cols_c2c<<<8448, 256, 0, stream>>>((float2*)B);
    // 9) h1 = sf_w1 @ [re(dcf); im(dcf)] + b      -> C
    conv1x1_kernel<64, 64, 0, true><<<516, 256, 0, stream>>>((const void*)B, sf_w1, sf_b1, Cs);
    // 10) h2 = dw3x3(h1) + sf_b2                  -> B
    dw3x3_kernel<<<66048, 256, 0, stream>>>(Cs, sf_w2, sf_b2, B, 64, 256, 129, 16908288);
    // 11) h3 = relu(sf_w3 @ h2 + b)               -> C
    conv1x1_kernel<64, 64, 1, false><<<516, 256, 0, stream>>>((const void*)B, sf_w3, sf_b3, Cs);
    // 12) spm = sigmoid(sf_w4 @ h3 + b)           -> B
    conv1x1_kernel<64, 32, 2, false><<<516, 256, 0, stream>>>((const void*)Cs, sf_w4, sf_b4, B);
    // 13) ycol = ifft_cols(xf * spm)              -> C (float2)
    ifft_cols_mask<<<8448, 256, 0, stream>>>((const float2*)A, B, (float2*)Cs);
    // 14) x_irfft = ifft_rows_c2r(ycol)           -> B
    ifft_rows_c2r<<<16384, 256, 0, stream>>>((const float2*)Cs, B);
    // 15) g = dw3x3(x_irfft) + fl_b1              -> A
    dw3x3_kernel<<<65536, 256, 0, stream>>>(B, fl_w1, fl_b1, A, 32, 256, 256, 16777216);
    // 16) out = fl_w2 @ (a * gelu(b)) + fl_b2 + input_flow  (overwrites X)
    final_kernel<<<2048, 256, 0, stream>>>(A, input_flow, fl_w2, fl_b2, out);
}

// Round 4
// 1499.672 us; speedup vs baseline: 1.2201x; 1.2201x over previous
//
#include <hip/hip_runtime.h>
#include <cmath>

// Problem constants
constexpr int kN = 8;
constexpr int kC = 32;
constexpr int kH = 256;
constexpr int kW = 256;
constexpr int kHW = kH * kW;     // 65536
constexpr int kWF = 129;         // W/2+1
constexpr int kHWF = kH * kWF;   // 33024
constexpr float kPI = 3.14159265358979323846f;

__device__ __forceinline__ float sigmoidf_(float x) { return 1.f / (1.f + expf(-x)); }

// XCD-contiguous swizzle: grid must be divisible by 8. Consecutive returned
// ids stay on one XCD (round-robin hardware dispatch assumed, learn_hip m09).
__device__ __forceinline__ int xcd_swizzle(int bid, int nblk)
{
    int chunk = nblk >> 3;
    return (bid & 7) * chunk + (bid >> 3);
}

// ---------------------------------------------------------------------------
// K1: LayerNorm over C (=32) + 1x1 conv (32->32) + ReLU.  Optionally a second
// weight set producing a second output (event branch feeds two 1x1 convs).
// ---------------------------------------------------------------------------
template <bool TWO>
__global__ __launch_bounds__(256) void lnmv_kernel(
    const float* __restrict__ in,
    const float* __restrict__ lng, const float* __restrict__ lnb,
    const float* __restrict__ w1, const float* __restrict__ b1, float* __restrict__ out1,
    const float* __restrict__ w2, const float* __restrict__ b2, float* __restrict__ out2)
{
    __shared__ __align__(16) float wl1[1024];
    __shared__ __align__(16) float wl2[TWO ? 1024 : 4];
    __shared__ float bl1[32], bl2[32], gl[32], bbl[32];
    int tid = threadIdx.x;
    for (int e = tid; e < 1024; e += 256) {
        wl1[e] = w1[e];
        if (TWO) wl2[e] = w2[e];
    }
    if (tid < 32) {
        bl1[tid] = b1[tid]; gl[tid] = lng[tid]; bbl[tid] = lnb[tid];
        if (TWO) bl2[tid] = b2[tid];
    }
    __syncthreads();

    int p = blockIdx.x * 256 + tid;         // < N*HW = 524288 exactly
    int n = p >> 16;
    int rem = p & 65535;
    const float* base = in + (size_t)n * kC * kHW + rem;

    float v[32];
    float mu = 0.f;
#pragma unroll
    for (int c = 0; c < 32; ++c) { v[c] = base[(size_t)c * kHW]; mu += v[c]; }
    mu *= 0.03125f;
    float var = 0.f;
#pragma unroll
    for (int c = 0; c < 32; ++c) { float d = v[c] - mu; var += d * d; }
    var *= 0.03125f;
    float rs = rsqrtf(var + 1e-5f);
#pragma unroll
    for (int c = 0; c < 32; ++c) v[c] = (v[c] - mu) * rs * gl[c] + bbl[c];

    {
        float* o = out1 + (size_t)n * kC * kHW + rem;
#pragma unroll
        for (int oc = 0; oc < 32; ++oc) {
            const float4* wr = reinterpret_cast<const float4*>(wl1 + oc * 32);
            float acc = bl1[oc];
#pragma unroll
            for (int q = 0; q < 8; ++q) {
                float4 wv = wr[q];
                acc += wv.x * v[4*q] + wv.y * v[4*q+1] + wv.z * v[4*q+2] + wv.w * v[4*q+3];
            }
            o[(size_t)oc * kHW] = fmaxf(acc, 0.f);
        }
    }
    if (TWO) {
        float* o = out2 + (size_t)n * kC * kHW + rem;
#pragma unroll
        for (int oc = 0; oc < 32; ++oc) {
            const float4* wr = reinterpret_cast<const float4*>(wl2 + oc * 32);
            float acc = bl2[oc];
#pragma unroll
            for (int q = 0; q < 8; ++q) {
                float4 wv = wr[q];
                acc += wv.x * v[4*q] + wv.y * v[4*q+1] + wv.z * v[4*q+2] + wv.w * v[4*q+3];
            }
            o[(size_t)oc * kHW] = fmaxf(acc, 0.f);
        }
    }
}

// ---------------------------------------------------------------------------
// K2: generic depthwise 3x3, pad 1, with bias. XCD-swizzled linear blocks.
// ---------------------------------------------------------------------------
__global__ __launch_bounds__(256) void dw3x3_kernel(
    const float* __restrict__ in, const float* __restrict__ w,
    const float* __restrict__ bias, float* __restrict__ out,
    int CH, int Hd, int Wd, int total)
{
    int sw = xcd_swizzle(blockIdx.x, gridDim.x);
    int idx = sw * 256 + threadIdx.x;
    if (idx >= total) return;
    int wx = idx % Wd;
    int rest = idx / Wd;
    int hy = rest % Hd;
    int pl = rest / Hd;          // n*CH + ch
    int ch = pl % CH;

    const float* ip = in + (size_t)pl * Hd * Wd;
    const float* wp = w + ch * 9;
    float acc = bias[ch];
#pragma unroll
    for (int dy = -1; dy <= 1; ++dy) {
        int yy = hy + dy;
        if (yy < 0 || yy >= Hd) continue;
        const float* rp = ip + (size_t)yy * Wd;
#pragma unroll
        for (int dx = -1; dx <= 1; ++dx) {
            int xx = wx + dx;
            if (xx < 0 || xx >= Wd) continue;
            acc += rp[xx] * wp[(dy + 1) * 3 + (dx + 1)];
        }
    }
    out[idx] = acc;
}

// ---------------------------------------------------------------------------
// K3: full 3x3 conv 32 -> COUT (pad 1). Block = 4 rows x 64 lanes, 4 px/thread.
// ---------------------------------------------------------------------------
template <int COUT, int COUTP, int ACT>
__global__ __launch_bounds__(256) void conv3x3_kernel(
    const float* __restrict__ in, const float* __restrict__ wg,
    const float* __restrict__ bias, float* __restrict__ out)
{
    __shared__ __align__(16) float wl[288 * COUTP];
    __shared__ float bl[COUT];
    int tid = threadIdx.x;
    for (int e = tid; e < 288 * COUTP; e += 256) {
        int oc = e % COUTP;
        int t = e / COUTP;                 // ic*9 + tap
        wl[e] = (oc < COUT) ? wg[(oc * 32 + (t / 9)) * 9 + (t % 9)] : 0.f;
    }
    if (tid < COUT) bl[tid] = bias[tid];
    __syncthreads();

    int sw = xcd_swizzle(blockIdx.x, gridDim.x);
    int row = sw * 4 + (tid >> 6);   // < N*H = 2048
    int lane = tid & 63;
    int n = row >> 8;
    int h = row & 255;

    float acc[4][COUTP];
#pragma unroll
    for (int px = 0; px < 4; ++px)
#pragma unroll
        for (int oc = 0; oc < COUTP; ++oc) acc[px][oc] = (oc < COUT) ? bl[oc] : 0.f;

    const float* ib = in + (size_t)n * 32 * kHW;
    for (int ic = 0; ic < 32; ++ic) {
        const float* ipl = ib + (size_t)ic * kHW;
#pragma unroll
        for (int ky = 0; ky < 3; ++ky) {
            int yy = h + ky - 1;
            if (yy < 0 || yy > 255) continue;
            const float* rp = ipl + (size_t)yy * 256;
#pragma unroll
            for (int kx = 0; kx < 3; ++kx) {
                float val[4];
#pragma unroll
                for (int px = 0; px < 4; ++px) {
                    int xx = lane + px * 64 + kx - 1;
                    val[px] = (xx >= 0 && xx < 256) ? rp[xx] : 0.f;
                }
                const float4* wr = reinterpret_cast<const float4*>(wl + (ic * 9 + ky * 3 + kx) * COUTP);
#pragma unroll
                for (int q = 0; q < COUTP / 4; ++q) {
                    float4 wv = wr[q];
#pragma unroll
                    for (int px = 0; px < 4; ++px) {
                        acc[px][4*q+0] += val[px] * wv.x;
                        acc[px][4*q+1] += val[px] * wv.y;
                        acc[px][4*q+2] += val[px] * wv.z;
                        acc[px][4*q+3] += val[px] * wv.w;
                    }
                }
            }
        }
    }

    float* ob = out + (size_t)n * COUT * kHW + (size_t)h * 256;
#pragma unroll
    for (int oc = 0; oc < COUT; ++oc) {
#pragma unroll
        for (int px = 0; px < 4; ++px) {
            float r = acc[px][oc];
            if (ACT == 2) r = sigmoidf_(r);
            ob[(size_t)oc * kHW + lane + px * 64] = r;
        }
    }
}

// ---------------------------------------------------------------------------
// K4: modulated deformable conv 3x3. Block = 4 rows x 64 lanes, 4 px/thread.
// XCD-swizzled so each XCD owns one image; tap re-reads hit that XCD's L2.
// ---------------------------------------------------------------------------
__global__ __launch_bounds__(256) void deform_kernel(
    const float* __restrict__ x, const float* __restrict__ off,
    const float* __restrict__ msk, const float* __restrict__ wt,
    float* __restrict__ out)
{
    __shared__ __align__(16) float wl[9 * 32 * 32];
    int tid = threadIdx.x;
    for (int e = tid; e < 9216; e += 256) {
        int o = e & 31;
        int t = e >> 5;
        int c = t & 31;
        int k = t >> 5;
        wl[e] = wt[((size_t)(o * 32 + c)) * 9 + k];
    }
    __syncthreads();

    int sw = xcd_swizzle(blockIdx.x, gridDim.x);   // 512 = 8 x 64: XCD j -> image j
    int row = sw * 4 + (tid >> 6);
    int lane = tid & 63;
    int n = row >> 8;
    int h = row & 255;
    int pixbase = h * 256 + lane;

    const float* offb = off + (size_t)n * 18 * kHW + pixbase;
    const float* mskb = msk + (size_t)n * 9 * kHW + pixbase;
    const float* xb = x + (size_t)n * 32 * kHW;

    float acc[4][32];
#pragma unroll
    for (int px = 0; px < 4; ++px)
#pragma unroll
        for (int oc = 0; oc < 32; ++oc) acc[px][oc] = 0.f;

    for (int k = 0; k < 9; ++k) {
        int ki = k / 3 - 1, kj = k % 3 - 1;
        int i00[4], i01[4], i10[4], i11[4];
        float w00[4], w01[4], w10[4], w11[4];
#pragma unroll
        for (int px = 0; px < 4; ++px) {
            int wx = lane + px * 64;
            float oy = offb[(size_t)(2 * k) * kHW + px * 64];
            float ox = offb[(size_t)(2 * k + 1) * kHW + px * 64];
            float m = mskb[(size_t)k * kHW + px * 64];
            float py = (float)(h + ki) + oy;
            float pxx = (float)(wx + kj) + ox;
            float y0f = floorf(py), x0f = floorf(pxx);
            float fy = py - y0f, fx = pxx - x0f;
            float vy0 = (y0f >= 0.f && y0f <= 255.f) ? 1.f : 0.f;
            float vy1 = (y0f >= -1.f && y0f <= 254.f) ? 1.f : 0.f;
            float vx0 = (x0f >= 0.f && x0f <= 255.f) ? 1.f : 0.f;
            float vx1 = (x0f >= -1.f && x0f <= 254.f) ? 1.f : 0.f;
            int y0 = min(max((int)y0f, 0), 255);
            int y1 = min(max((int)y0f + 1, 0), 255);
            int x0 = min(max((int)x0f, 0), 255);
            int x1 = min(max((int)x0f + 1, 0), 255);
            i00[px] = y0 * 256 + x0; i01[px] = y0 * 256 + x1;
            i10[px] = y1 * 256 + x0; i11[px] = y1 * 256 + x1;
            w00[px] = (1.f - fy) * (1.f - fx) * m * vy0 * vx0;
            w01[px] = (1.f - fy) * fx * m * vy0 * vx1;
            w10[px] = fy * (1.f - fx) * m * vy1 * vx0;
            w11[px] = fy * fx * m * vy1 * vx1;
        }
        for (int c = 0; c < 32; ++c) {
            const float* xp = xb + (size_t)c * kHW;
            float s[4];
#pragma unroll
            for (int px = 0; px < 4; ++px) {
                s[px] = w00[px] * xp[i00[px]] + w01[px] * xp[i01[px]] +
                        w10[px] * xp[i10[px]] + w11[px] * xp[i11[px]];
            }
            const float4* wr = reinterpret_cast<const float4*>(wl + (size_t)(k * 32 + c) * 32);
#pragma unroll
            for (int q = 0; q < 8; ++q) {
                float4 wv = wr[q];
#pragma unroll
                for (int px = 0; px < 4; ++px) {
                    acc[px][4*q+0] += s[px] * wv.x;
                    acc[px][4*q+1] += s[px] * wv.y;
                    acc[px][4*q+2] += s[px] * wv.z;
                    acc[px][4*q+3] += s[px] * wv.w;
                }
            }
        }
    }

    float* ob = out + (size_t)n * 32 * kHW + pixbase;
#pragma unroll
    for (int oc = 0; oc < 32; ++oc)
#pragma unroll
        for (int px = 0; px < 4; ++px)
            ob[(size_t)oc * kHW + px * 64] = acc[px][oc];
}

// ---------------------------------------------------------------------------
// FFT-256: radix-4 Stockham in LDS (exact fusion of two verified radix-2
// stages). 64 lanes per FFT, 4 points/lane/stage, 4 stages. tw[t] =
// exp(-2*pi*i*t/256), t in [0,128). sgn=+1 fwd, -1 inv. Ends in A, natural
// order.
// ---------------------------------------------------------------------------
__device__ __forceinline__ void fft256_stages(float2* A, float2* Bb, const float2* tw,
                                              int lane, float sgn)
{
    float2* src = A;
    float2* dst = Bb;
#pragma unroll
    for (int s = 0; s < 4; ++s) {
        int m = 1 << (2 * s);            // 1,4,16,64
        int r = lane & (m - 1);
        int mc = lane - r;               // m * floor(lane/m)
        __syncthreads();
        float2 x0 = src[lane];
        float2 x1 = src[lane + 128];
        float2 x2 = src[lane + 64];
        float2 x3 = src[lane + 192];
        float2 wa = tw[mc];
        float2 wb = tw[mc + 64];
        float2 wc = tw[2 * mc];
        float way = wa.y * sgn, wby = wb.y * sgn, wcy = wc.y * sgn;
        // radix-2 stage m, butterfly q=lane:   e1, o1
        float e1x = x0.x + x1.x, e1y = x0.y + x1.y;
        float d1x = x0.x - x1.x, d1y = x0.y - x1.y;
        float o1x = wa.x * d1x - way * d1y, o1y = wa.x * d1y + way * d1x;
        // radix-2 stage m, butterfly q=lane+64: e2, o2
        float e2x = x2.x + x3.x, e2y = x2.y + x3.y;
        float d2x = x2.x - x3.x, d2y = x2.y - x3.y;
        float o2x = wb.x * d2x - wby * d2y, o2y = wb.x * d2y + wby * d2x;
        // radix-2 stage 2m on (e1,e2) and (o1,o2), shared twiddle wc
        int base = r + 4 * mc;
        float2 y0; y0.x = e1x + e2x; y0.y = e1y + e2y;
        float ex = e1x - e2x, ey = e1y - e2y;
        float2 y2; y2.x = wc.x * ex - wcy * ey; y2.y = wc.x * ey + wcy * ex;
        float2 y1; y1.x = o1x + o2x; y1.y = o1y + o2y;
        float ox = o1x - o2x, oy = o1y - o2y;
        float2 y3; y3.x = wc.x * ox - wcy * oy; y3.y = wc.x * oy + wcy * ox;
        dst[base] = y0;
        dst[base + m] = y1;
        dst[base + 2 * m] = y2;
        dst[base + 3 * m] = y3;
        float2* t = src; src = dst; dst = t;
    }
    __syncthreads();
}

__device__ __forceinline__ void make_tw(float2* tw, int tid)
{
    if (tid < 128) {
        float ang = -kPI * (float)tid / 128.f;  // -2*pi*t/256
        float2 w; w.x = cosf(ang); w.y = sinf(ang);
        tw[tid] = w;
    }
}

// rows: real 256 -> 129 complex bins. 4 rows per block.
__global__ __launch_bounds__(256) void fft_rows_r2c(const float* __restrict__ in,
                                                    float2* __restrict__ out)
{
    __shared__ float2 A[4][256];
    __shared__ float2 Bb[4][256];
    __shared__ float2 tw[128];
    int tid = threadIdx.x;
    int sub = tid >> 6, lane = tid & 63;
    make_tw(tw, tid);
    size_t row = (size_t)blockIdx.x * 4 + sub;
    const float* rp = in + row * 256;
#pragma unroll
    for (int r = 0; r < 4; ++r) {
        int i = lane + 64 * r;
        float2 a; a.x = rp[i]; a.y = 0.f;
        A[sub][i] = a;
    }
    fft256_stages(A[sub], Bb[sub], tw, lane, 1.f);
    float2* op = out + row * kWF;
    op[lane] = A[sub][lane];
    op[lane + 64] = A[sub][lane + 64];
    if (lane == 0) op[128] = A[sub][128];
}

// cols: in-place complex FFT over H for 4 adjacent columns per block.
__global__ __launch_bounds__(256) void fft_cols_c2c(float2* __restrict__ buf)
{
    __shared__ float2 A[4][256];
    __shared__ float2 Bb[4][256];
    __shared__ float2 tw[128];
    int tid = threadIdx.x;
    int sub = tid >> 6, lane = tid & 63;
    make_tw(tw, tid);
    int b = xcd_swizzle(blockIdx.x, gridDim.x);   // 8448 = 8 x 1056
    int p = b / 33;
    int col0 = (b % 33) * 4;
    int ncols = (col0 + 4 <= kWF) ? 4 : (kWF - col0);
    float2* base = buf + (size_t)p * kHWF + col0;
    for (int e = tid; e < 1024; e += 256) {
        int cc = e & 3, hh = e >> 2;
        if (cc < ncols) A[cc][hh] = base[(size_t)hh * kWF + cc];
    }
    fft256_stages(A[sub], Bb[sub], tw, lane, 1.f);
    for (int e = tid; e < 1024; e += 256) {
        int cc = e & 3, hh = e >> 2;
        if (cc < ncols) base[(size_t)hh * kWF + cc] = A[cc][hh];
    }
}

// inverse col FFT of (xf * real_mask), out-of-place.
__global__ __launch_bounds__(256) void ifft_cols_mask(const float2* __restrict__ xf,
                                                      const float* __restrict__ spm,
                                                      float2* __restrict__ out)
{
    __shared__ float2 A[4][256];
    __shared__ float2 Bb[4][256];
    __shared__ float2 tw[128];
    int tid = threadIdx.x;
    int sub = tid >> 6, lane = tid & 63;
    make_tw(tw, tid);
    int b = xcd_swizzle(blockIdx.x, gridDim.x);
    int p = b / 33;
    int col0 = (b % 33) * 4;
    int ncols = (col0 + 4 <= kWF) ? 4 : (kWF - col0);
    const float2* xb = xf + (size_t)p * kHWF + col0;
    const float* mb = spm + (size_t)p * kHWF + col0;
    for (int e = tid; e < 1024; e += 256) {
        int cc = e & 3, hh = e >> 2;
        if (cc < ncols) {
            float2 a = xb[(size_t)hh * kWF + cc];
            float m = mb[(size_t)hh * kWF + cc];
            a.x *= m; a.y *= m;
            A[cc][hh] = a;
        }
    }
    fft256_stages(A[sub], Bb[sub], tw, lane, -1.f);
    float2* ob = out + (size_t)p * kHWF + col0;
    for (int e = tid; e < 1024; e += 256) {
        int cc = e & 3, hh = e >> 2;
        if (cc < ncols) ob[(size_t)hh * kWF + cc] = A[cc][hh];
    }
}

// rows inverse: 129 complex (Hermitian-extended) -> 256 real, scaled 1/65536.
__global__ __launch_bounds__(256) void ifft_rows_c2r(const float2* __restrict__ in,
                                                     float* __restrict__ out)
{
    __shared__ float2 A[4][256];
    __shared__ float2 Bb[4][256];
    __shared__ float2 tw[128];
    int tid = threadIdx.x;
    int sub = tid >> 6, lane = tid & 63;
    make_tw(tw, tid);
    size_t row = (size_t)blockIdx.x * 4 + sub;
    const float2* ip = in + row * kWF;
#pragma unroll
    for (int r = 0; r < 4; ++r) {
        int k = lane + 64 * r;
        if (k <= 128) {
            A[sub][k] = ip[k];
        } else {
            float2 c = ip[256 - k];
            c.y = -c.y;
            A[sub][k] = c;
        }
    }
    fft256_stages(A[sub], Bb[sub], tw, lane, -1.f);
    float* op = out + row * 256;
#pragma unroll
    for (int r = 0; r < 4; ++r) {
        int k = lane + 64 * r;
        op[k] = A[sub][k].x * (1.f / 65536.f);
    }
}

// ---------------------------------------------------------------------------
// 1x1 conv on the frequency-domain planes. 2 px/thread.
// ---------------------------------------------------------------------------
template <int CIN, int COUT, int ACT, bool CPLX>
__global__ __launch_bounds__(256) void conv1x1_kernel(
    const void* __restrict__ inv, const float* __restrict__ wg,
    const float* __restrict__ bias, float* __restrict__ out)
{
    constexpr int PL = kHWF;
    __shared__ __align__(16) float wl[COUT * CIN];
    __shared__ float bl[COUT];
    int tid = threadIdx.x;
    for (int e = tid; e < COUT * CIN; e += 256) wl[e] = wg[e];
    if (tid < COUT) bl[tid] = bias[tid];
    __syncthreads();

    int p0 = blockIdx.x * 512 + tid;
    int p1 = p0 + 256;
    int n0 = p0 / PL, r0 = p0 % PL;
    int n1 = p1 / PL, r1 = p1 % PL;

    float v0[CIN], v1[CIN];
    if (CPLX) {
        const float2* in2 = (const float2*)inv;
#pragma unroll
        for (int c = 0; c < 32; ++c) {
            float2 a = in2[(size_t)(n0 * 32 + c) * PL + r0];
            float2 b = in2[(size_t)(n1 * 32 + c) * PL + r1];
            v0[c] = a.x; v0[32 + c] = a.y;
            v1[c] = b.x; v1[32 + c] = b.y;
        }
    } else {
        const float* inf_ = (const float*)inv;
#pragma unroll
        for (int c = 0; c < CIN; ++c) {
            v0[c] = inf_[(size_t)(n0 * CIN + c) * PL + r0];
            v1[c] = inf_[(size_t)(n1 * CIN + c) * PL + r1];
        }
    }

#pragma unroll
    for (int oc = 0; oc < COUT; ++oc) {
        const float4* wr = reinterpret_cast<const float4*>(wl + oc * CIN);
        float a0 = bl[oc], a1 = bl[oc];
#pragma unroll
        for (int q = 0; q < CIN / 4; ++q) {
            float4 wv = wr[q];
            a0 += wv.x * v0[4*q] + wv.y * v0[4*q+1] + wv.z * v0[4*q+2] + wv.w * v0[4*q+3];
            a1 += wv.x * v1[4*q] + wv.y * v1[4*q+1] + wv.z * v1[4*q+2] + wv.w * v1[4*q+3];
        }
        if (ACT == 1) { a0 = fmaxf(a0, 0.f); a1 = fmaxf(a1, 0.f); }
        if (ACT == 2) { a0 = sigmoidf_(a0); a1 = sigmoidf_(a1); }
        out[(size_t)(n0 * COUT + oc) * PL + r0] = a0;
        out[(size_t)(n1 * COUT + oc) * PL + r1] = a1;
    }
}

// ---------------------------------------------------------------------------
// Fused steps 11+12: spm = sigmoid(w4 @ relu(w3 @ h2 + b3) + b4). 2 px/thread.
// Saves one full 64-ch plane write + read.
// ---------------------------------------------------------------------------
__global__ __launch_bounds__(256) void conv1x1_chain_kernel(
    const float* __restrict__ in, const float* __restrict__ w3,
    const float* __restrict__ b3, const float* __restrict__ w4,
    const float* __restrict__ b4, float* __restrict__ out)
{
    constexpr int PL = kHWF;
    __shared__ __align__(16) float wl3[64 * 64];
    __shared__ __align__(16) float wl4[32 * 64];
    __shared__ float bl3[64], bl4[32];
    int tid = threadIdx.x;
    for (int e = tid; e < 4096; e += 256) wl3[e] = w3[e];
    for (int e = tid; e < 2048; e += 256) wl4[e] = w4[e];
    if (tid < 64) bl3[tid] = b3[tid];
    if (tid < 32) bl4[tid] = b4[tid];
    __syncthreads();

    int p0 = blockIdx.x * 512 + tid;
    int p1 = p0 + 256;
    int n0 = p0 / PL, r0 = p0 % PL;
    int n1 = p1 / PL, r1 = p1 % PL;

    float v0[64], v1[64];
#pragma unroll
    for (int c = 0; c < 64; ++c) {
        v0[c] = in[(size_t)(n0 * 64 + c) * PL + r0];
        v1[c] = in[(size_t)(n1 * 64 + c) * PL + r1];
    }

    float t0[64], t1[64];
#pragma unroll
    for (int oc = 0; oc < 64; ++oc) {
        const float4* wr = reinterpret_cast<const float4*>(wl3 + oc * 64);
        float a0 = bl3[oc], a1 = bl3[oc];
#pragma unroll
        for (int q = 0; q < 16; ++q) {
            float4 wv = wr[q];
            a0 += wv.x * v0[4*q] + wv.y * v0[4*q+1] + wv.z * v0[4*q+2] + wv.w * v0[4*q+3];
            a1 += wv.x * v1[4*q] + wv.y * v1[4*q+1] + wv.z * v1[4*q+2] + wv.w * v1[4*q+3];
        }
        t0[oc] = fmaxf(a0, 0.f); t1[oc] = fmaxf(a1, 0.f);
    }

#pragma unroll
    for (int oc = 0; oc < 32; ++oc) {
        const float4* wr = reinterpret_cast<const float4*>(wl4 + oc * 64);
        float a0 = bl4[oc], a1 = bl4[oc];
#pragma unroll
        for (int q = 0; q < 16; ++q) {
            float4 wv = wr[q];
            a0 += wv.x * t0[4*q] + wv.y * t0[4*q+1] + wv.z * t0[4*q+2] + wv.w * t0[4*q+3];
            a1 += wv.x * t1[4*q] + wv.y * t1[4*q+1] + wv.z * t1[4*q+2] + wv.w * t1[4*q+3];
        }
        out[(size_t)(n0 * 32 + oc) * PL + r0] = sigmoidf_(a0);
        out[(size_t)(n1 * 32 + oc) * PL + r1] = sigmoidf_(a1);
    }
}

// ---------------------------------------------------------------------------
// Final: GLU with exact gelu, 1x1 conv 16->32, bias, + residual input_flow.
// ---------------------------------------------------------------------------
__global__ __launch_bounds__(256) void final_kernel(
    const float* __restrict__ g, const float* __restrict__ flow,
    const float* __restrict__ wg, const float* __restrict__ bias,
    float* __restrict__ out)
{
    __shared__ __align__(16) float wl[32 * 16];
    __shared__ float bl[32];
    int tid = threadIdx.x;
    for (int e = tid; e < 512; e += 256) wl[e] = wg[e];
    if (tid < 32) bl[tid] = bias[tid];
    __syncthreads();

    int p = blockIdx.x * 256 + tid;
    int n = p >> 16;
    int rem = p & 65535;
    const float* gb = g + (size_t)n * 32 * kHW + rem;

    float v[16];
#pragma unroll
    for (int c = 0; c < 16; ++c) {
        float a = gb[(size_t)c * kHW];
        float b = gb[(size_t)(16 + c) * kHW];
        float ge = 0.5f * b * (1.f + erff(b * 0.70710678118654752f));
        v[c] = a * ge;
    }

    const float* fb = flow + (size_t)n * 32 * kHW + rem;
    float* ob = out + (size_t)n * 32 * kHW + rem;
#pragma unroll
    for (int oc = 0; oc < 32; ++oc) {
        const float4* wr = reinterpret_cast<const float4*>(wl + oc * 16);
        float acc = bl[oc];
#pragma unroll
        for (int q = 0; q < 4; ++q) {
            float4 wv = wr[q];
            acc += wv.x * v[4*q] + wv.y * v[4*q+1] + wv.z * v[4*q+2] + wv.w * v[4*q+3];
        }
        ob[(size_t)oc * kHW] = acc + fb[(size_t)oc * kHW];
    }
}

// ---------------------------------------------------------------------------
// Buffer plan (3 ws slots of 16,908,288 floats + d_out):
//   A: t1 -> offset -> xf(complex, live 7..13) -> g
//   B: t2 -> mask -> dcf -> h2 -> ycol
//   C: t3 -> dc -> h1 -> spm -> x_irfft
//   d_out: x (steps 3..7) -> final output
// ---------------------------------------------------------------------------
extern "C" void kernel_launch(void* const* d_in, const int* in_sizes, int n_in,
                              void* d_out, int out_size, void* d_ws, size_t ws_size,
                              hipStream_t stream)
{
    (void)in_sizes; (void)n_in; (void)out_size; (void)ws_size;

    const float* input_flow  = (const float*)d_in[0];
    const float* input_event = (const float*)d_in[1];
    const float* ln_flow_g   = (const float*)d_in[2];
    const float* ln_flow_b   = (const float*)d_in[3];
    const float* ln_event_g  = (const float*)d_in[4];
    const float* ln_event_b  = (const float*)d_in[5];
    const float* ff_w1 = (const float*)d_in[6];
    const float* ff_b1 = (const float*)d_in[7];
    const float* ff_w2 = (const float*)d_in[8];
    const float* ff_b2 = (const float*)d_in[9];
    const float* fo_w1 = (const float*)d_in[10];
    const float* fo_b1 = (const float*)d_in[11];
    const float* fo_w2 = (const float*)d_in[12];
    const float* fo_b2 = (const float*)d_in[13];
    const float* fm_w1 = (const float*)d_in[14];
    const float* fm_b1 = (const float*)d_in[15];
    const float* fm_w2 = (const float*)d_in[16];
    const float* fm_b2 = (const float*)d_in[17];
    const float* dc_weight = (const float*)d_in[18];
    const float* sf_w1 = (const float*)d_in[19];
    const float* sf_b1 = (const float*)d_in[20];
    const float* sf_w2 = (const float*)d_in[21];
    const float* sf_b2 = (const float*)d_in[22];
    const float* sf_w3 = (const float*)d_in[23];
    const float* sf_b3 = (const float*)d_in[24];
    const float* sf_w4 = (const float*)d_in[25];
    const float* sf_b4 = (const float*)d_in[26];
    const float* fl_w1 = (const float*)d_in[27];
    const float* fl_b1 = (const float*)d_in[28];
    const float* fl_w2 = (const float*)d_in[29];
    const float* fl_b2 = (const float*)d_in[30];
    float* out = (float*)d_out;

    const size_t S = (size_t)16908288;
    float* A = (float*)d_ws;
    float* B = A + S;
    float* Cs = B + S;
    float* X = out;   // x lives in d_out between steps 3 and 7

    // 1) t1 = relu(ff_w1 @ LN(flow))              -> A
    lnmv_kernel<false><<<2048, 256, 0, stream>>>(input_flow, ln_flow_g, ln_flow_b,
                                                 ff_w1, ff_b1, A,
                                                 nullptr, nullptr, nullptr);
    // 2) t2 = relu(fo_w1 @ LN(event)) -> B ; t3 = relu(fm_w1 @ LN(event)) -> C
    lnmv_kernel<true><<<2048, 256, 0, stream>>>(input_event, ln_event_g, ln_event_b,
                                                fo_w1, fo_b1, B,
                                                fm_w1, fm_b1, Cs);
    // 3) x = dw3x3(t1) + ff_b2                    -> X (d_out)
    dw3x3_kernel<<<65536, 256, 0, stream>>>(A, ff_w2, ff_b2, X, 32, 256, 256, 16777216);
    // 4) offset = conv3x3(t2)                     -> A
    conv3x3_kernel<18, 20, 0><<<512, 256, 0, stream>>>(B, fo_w2, fo_b2, A);
    // 5) mask = sigmoid(conv3x3(t3))              -> B
    conv3x3_kernel<9, 12, 2><<<512, 256, 0, stream>>>(Cs, fm_w2, fm_b2, B);
    // 6) dc = deform(x, offset, mask)             -> C
    deform_kernel<<<512, 256, 0, stream>>>(X, A, B, dc_weight, Cs);
    // 7) xf = rfft2(x)                            -> A (float2)
    fft_rows_r2c<<<16384, 256, 0, stream>>>(X, (float2*)A);
    fft_cols_c2c<<<8448, 256, 0, stream>>>((float2*)A);
    // 8) dcf = rfft2(dc)                          -> B (float2)
    fft_rows_r2c<<<16384, 256, 0, stream>>>(Cs, (float2*)B);
    fft_cols_c2c<<<8448, 256, 0, stream>>>((float2*)B);
    // 9) h1 = sf_w1 @ [re(dcf); im(dcf)] + b      -> C
    conv1x1_kernel<64, 64, 0, true><<<516, 256, 0, stream>>>((const void*)B, sf_w1, sf_b1, Cs);
    // 10) h2 = dw3x3(h1) + sf_b2                  -> B
    dw3x3_kernel<<<66048, 256, 0, stream>>>(Cs, sf_w2, sf_b2, B, 64, 256, 129, 16908288);
    // 11+12) spm = sigmoid(w4 @ relu(w3 @ h2))    -> C
    conv1x1_chain_kernel<<<516, 256, 0, stream>>>(B, sf_w3, sf_b3, sf_w4, sf_b4, Cs);
    // 13) ycol = ifft_cols(xf * spm)              -> B (float2)
    ifft_cols_mask<<<8448, 256, 0, stream>>>((const float2*)A, Cs, (float2*)B);
    // 14) x_irfft = ifft_rows_c2r(ycol)           -> C
    ifft_rows_c2r<<<16384, 256, 0, stream>>>((const float2*)B, Cs);
    // 15) g = dw3x3(x_irfft) + fl_b1              -> A
    dw3x3_kernel<<<65536, 256, 0, stream>>>(Cs, fl_w1, fl_b1, A, 32, 256, 256, 16777216);
    // 16) out = fl_w2 @ (a * gelu(b)) + fl_b2 + input_flow  (overwrites X)
    final_kernel<<<2048, 256, 0, stream>>>(A, input_flow, fl_w2, fl_b2, out);
}

// Round 5
// 1446.651 us; speedup vs baseline: 1.2648x; 1.0367x over previous
//
#include <hip/hip_runtime.h>
#include <cmath>

// Problem constants
constexpr int kN = 8;
constexpr int kC = 32;
constexpr int kH = 256;
constexpr int kW = 256;
constexpr int kHW = kH * kW;     // 65536
constexpr int kWF = 129;         // W/2+1
constexpr int kHWF = kH * kWF;   // 33024
constexpr float kPI = 3.14159265358979323846f;

__device__ __forceinline__ float sigmoidf_(float x) { return 1.f / (1.f + expf(-x)); }

// XCD-contiguous swizzle: grid must be divisible by 8.
__device__ __forceinline__ int xcd_swizzle(int bid, int nblk)
{
    int chunk = nblk >> 3;
    return (bid & 7) * chunk + (bid >> 3);
}

// ---------------------------------------------------------------------------
// K1: LayerNorm over C (=32) + 1x1 conv (32->32) + ReLU (optionally two sets).
// ---------------------------------------------------------------------------
template <bool TWO>
__global__ __launch_bounds__(256) void lnmv_kernel(
    const float* __restrict__ in,
    const float* __restrict__ lng, const float* __restrict__ lnb,
    const float* __restrict__ w1, const float* __restrict__ b1, float* __restrict__ out1,
    const float* __restrict__ w2, const float* __restrict__ b2, float* __restrict__ out2)
{
    __shared__ __align__(16) float wl1[1024];
    __shared__ __align__(16) float wl2[TWO ? 1024 : 4];
    __shared__ float bl1[32], bl2[32], gl[32], bbl[32];
    int tid = threadIdx.x;
    for (int e = tid; e < 1024; e += 256) {
        wl1[e] = w1[e];
        if (TWO) wl2[e] = w2[e];
    }
    if (tid < 32) {
        bl1[tid] = b1[tid]; gl[tid] = lng[tid]; bbl[tid] = lnb[tid];
        if (TWO) bl2[tid] = b2[tid];
    }
    __syncthreads();

    int p = blockIdx.x * 256 + tid;         // < N*HW = 524288 exactly
    int n = p >> 16;
    int rem = p & 65535;
    const float* base = in + (size_t)n * kC * kHW + rem;

    float v[32];
    float mu = 0.f;
#pragma unroll
    for (int c = 0; c < 32; ++c) { v[c] = base[(size_t)c * kHW]; mu += v[c]; }
    mu *= 0.03125f;
    float var = 0.f;
#pragma unroll
    for (int c = 0; c < 32; ++c) { float d = v[c] - mu; var += d * d; }
    var *= 0.03125f;
    float rs = rsqrtf(var + 1e-5f);
#pragma unroll
    for (int c = 0; c < 32; ++c) v[c] = (v[c] - mu) * rs * gl[c] + bbl[c];

    {
        float* o = out1 + (size_t)n * kC * kHW + rem;
#pragma unroll
        for (int oc = 0; oc < 32; ++oc) {
            const float4* wr = reinterpret_cast<const float4*>(wl1 + oc * 32);
            float acc = bl1[oc];
#pragma unroll
            for (int q = 0; q < 8; ++q) {
                float4 wv = wr[q];
                acc += wv.x * v[4*q] + wv.y * v[4*q+1] + wv.z * v[4*q+2] + wv.w * v[4*q+3];
            }
            o[(size_t)oc * kHW] = fmaxf(acc, 0.f);
        }
    }
    if (TWO) {
        float* o = out2 + (size_t)n * kC * kHW + rem;
#pragma unroll
        for (int oc = 0; oc < 32; ++oc) {
            const float4* wr = reinterpret_cast<const float4*>(wl2 + oc * 32);
            float acc = bl2[oc];
#pragma unroll
            for (int q = 0; q < 8; ++q) {
                float4 wv = wr[q];
                acc += wv.x * v[4*q] + wv.y * v[4*q+1] + wv.z * v[4*q+2] + wv.w * v[4*q+3];
            }
            o[(size_t)oc * kHW] = fmaxf(acc, 0.f);
        }
    }
}

// ---------------------------------------------------------------------------
// K2: generic depthwise 3x3, pad 1, with bias.
// ---------------------------------------------------------------------------
__global__ __launch_bounds__(256) void dw3x3_kernel(
    const float* __restrict__ in, const float* __restrict__ w,
    const float* __restrict__ bias, float* __restrict__ out,
    int CH, int Hd, int Wd, int total)
{
    int sw = xcd_swizzle(blockIdx.x, gridDim.x);
    int idx = sw * 256 + threadIdx.x;
    if (idx >= total) return;
    int wx = idx % Wd;
    int rest = idx / Wd;
    int hy = rest % Hd;
    int pl = rest / Hd;          // n*CH + ch
    int ch = pl % CH;

    const float* ip = in + (size_t)pl * Hd * Wd;
    const float* wp = w + ch * 9;
    float acc = bias[ch];
#pragma unroll
    for (int dy = -1; dy <= 1; ++dy) {
        int yy = hy + dy;
        if (yy < 0 || yy >= Hd) continue;
        const float* rp = ip + (size_t)yy * Wd;
#pragma unroll
        for (int dx = -1; dx <= 1; ++dx) {
            int xx = wx + dx;
            if (xx < 0 || xx >= Wd) continue;
            acc += rp[xx] * wp[(dy + 1) * 3 + (dx + 1)];
        }
    }
    out[idx] = acc;
}

// ---------------------------------------------------------------------------
// K3: full 3x3 conv 32 -> COUT (pad 1). Block = 4 rows x 64 lanes, 4 px/thread.
// ---------------------------------------------------------------------------
template <int COUT, int COUTP, int ACT>
__global__ __launch_bounds__(256) void conv3x3_kernel(
    const float* __restrict__ in, const float* __restrict__ wg,
    const float* __restrict__ bias, float* __restrict__ out)
{
    __shared__ __align__(16) float wl[288 * COUTP];
    __shared__ float bl[COUT];
    int tid = threadIdx.x;
    for (int e = tid; e < 288 * COUTP; e += 256) {
        int oc = e % COUTP;
        int t = e / COUTP;                 // ic*9 + tap
        wl[e] = (oc < COUT) ? wg[(oc * 32 + (t / 9)) * 9 + (t % 9)] : 0.f;
    }
    if (tid < COUT) bl[tid] = bias[tid];
    __syncthreads();

    int sw = xcd_swizzle(blockIdx.x, gridDim.x);
    int row = sw * 4 + (tid >> 6);   // < N*H = 2048
    int lane = tid & 63;
    int n = row >> 8;
    int h = row & 255;

    float acc[4][COUTP];
#pragma unroll
    for (int px = 0; px < 4; ++px)
#pragma unroll
        for (int oc = 0; oc < COUTP; ++oc) acc[px][oc] = (oc < COUT) ? bl[oc] : 0.f;

    const float* ib = in + (size_t)n * 32 * kHW;
    for (int ic = 0; ic < 32; ++ic) {
        const float* ipl = ib + (size_t)ic * kHW;
#pragma unroll
        for (int ky = 0; ky < 3; ++ky) {
            int yy = h + ky - 1;
            if (yy < 0 || yy > 255) continue;
            const float* rp = ipl + (size_t)yy * 256;
#pragma unroll
            for (int kx = 0; kx < 3; ++kx) {
                float val[4];
#pragma unroll
                for (int px = 0; px < 4; ++px) {
                    int xx = lane + px * 64 + kx - 1;
                    val[px] = (xx >= 0 && xx < 256) ? rp[xx] : 0.f;
                }
                const float4* wr = reinterpret_cast<const float4*>(wl + (ic * 9 + ky * 3 + kx) * COUTP);
#pragma unroll
                for (int q = 0; q < COUTP / 4; ++q) {
                    float4 wv = wr[q];
#pragma unroll
                    for (int px = 0; px < 4; ++px) {
                        acc[px][4*q+0] += val[px] * wv.x;
                        acc[px][4*q+1] += val[px] * wv.y;
                        acc[px][4*q+2] += val[px] * wv.z;
                        acc[px][4*q+3] += val[px] * wv.w;
                    }
                }
            }
        }
    }

    float* ob = out + (size_t)n * COUT * kHW + (size_t)h * 256;
#pragma unroll
    for (int oc = 0; oc < COUT; ++oc) {
#pragma unroll
        for (int px = 0; px < 4; ++px) {
            float r = acc[px][oc];
            if (ACT == 2) r = sigmoidf_(r);
            ob[(size_t)oc * kHW + lane + px * 64] = r;
        }
    }
}

// ---------------------------------------------------------------------------
// K4: modulated deformable conv 3x3. Block = 2 rows x 128 threads, 2 px/thread.
// Grid 1024 (= 4 blocks/CU -> 16 waves/CU; LDS 36 KB caps at 4 blocks/CU).
// ---------------------------------------------------------------------------
__global__ __launch_bounds__(256) void deform_kernel(
    const float* __restrict__ x, const float* __restrict__ off,
    const float* __restrict__ msk, const float* __restrict__ wt,
    float* __restrict__ out)
{
    __shared__ __align__(16) float wl[9 * 32 * 32];
    int tid = threadIdx.x;
    for (int e = tid; e < 9216; e += 256) {
        int o = e & 31;
        int t = e >> 5;
        int c = t & 31;
        int k = t >> 5;
        wl[e] = wt[((size_t)(o * 32 + c)) * 9 + k];
    }
    __syncthreads();

    int sw = xcd_swizzle(blockIdx.x, gridDim.x);   // 1024 = 8 x 128: XCD j -> image j
    int halfid = tid >> 7;                          // 0/1: which row of the block
    int l = tid & 127;
    int row = sw * 2 + halfid;
    int n = row >> 8;
    int h = row & 255;
    int pixbase = h * 256 + l;

    const float* offb = off + (size_t)n * 18 * kHW + pixbase;
    const float* mskb = msk + (size_t)n * 9 * kHW + pixbase;
    const float* xb = x + (size_t)n * 32 * kHW;

    float acc[2][32];
#pragma unroll
    for (int px = 0; px < 2; ++px)
#pragma unroll
        for (int oc = 0; oc < 32; ++oc) acc[px][oc] = 0.f;

    for (int k = 0; k < 9; ++k) {
        int ki = k / 3 - 1, kj = k % 3 - 1;
        int i00[2], i01[2], i10[2], i11[2];
        float w00[2], w01[2], w10[2], w11[2];
#pragma unroll
        for (int px = 0; px < 2; ++px) {
            int wx = l + px * 128;
            float oy = offb[(size_t)(2 * k) * kHW + px * 128];
            float ox = offb[(size_t)(2 * k + 1) * kHW + px * 128];
            float m = mskb[(size_t)k * kHW + px * 128];
            float py = (float)(h + ki) + oy;
            float pxx = (float)(wx + kj) + ox;
            float y0f = floorf(py), x0f = floorf(pxx);
            float fy = py - y0f, fx = pxx - x0f;
            float vy0 = (y0f >= 0.f && y0f <= 255.f) ? 1.f : 0.f;
            float vy1 = (y0f >= -1.f && y0f <= 254.f) ? 1.f : 0.f;
            float vx0 = (x0f >= 0.f && x0f <= 255.f) ? 1.f : 0.f;
            float vx1 = (x0f >= -1.f && x0f <= 254.f) ? 1.f : 0.f;
            int y0 = min(max((int)y0f, 0), 255);
            int y1 = min(max((int)y0f + 1, 0), 255);
            int x0 = min(max((int)x0f, 0), 255);
            int x1 = min(max((int)x0f + 1, 0), 255);
            i00[px] = y0 * 256 + x0; i01[px] = y0 * 256 + x1;
            i10[px] = y1 * 256 + x0; i11[px] = y1 * 256 + x1;
            w00[px] = (1.f - fy) * (1.f - fx) * m * vy0 * vx0;
            w01[px] = (1.f - fy) * fx * m * vy0 * vx1;
            w10[px] = fy * (1.f - fx) * m * vy1 * vx0;
            w11[px] = fy * fx * m * vy1 * vx1;
        }
#pragma unroll 2
        for (int c = 0; c < 32; ++c) {
            const float* xp = xb + (size_t)c * kHW;
            float s[2];
#pragma unroll
            for (int px = 0; px < 2; ++px) {
                s[px] = w00[px] * xp[i00[px]] + w01[px] * xp[i01[px]] +
                        w10[px] * xp[i10[px]] + w11[px] * xp[i11[px]];
            }
            const float4* wr = reinterpret_cast<const float4*>(wl + (size_t)(k * 32 + c) * 32);
#pragma unroll
            for (int q = 0; q < 8; ++q) {
                float4 wv = wr[q];
#pragma unroll
                for (int px = 0; px < 2; ++px) {
                    acc[px][4*q+0] += s[px] * wv.x;
                    acc[px][4*q+1] += s[px] * wv.y;
                    acc[px][4*q+2] += s[px] * wv.z;
                    acc[px][4*q+3] += s[px] * wv.w;
                }
            }
        }
    }

    float* ob = out + (size_t)n * 32 * kHW + pixbase;
#pragma unroll
    for (int oc = 0; oc < 32; ++oc)
#pragma unroll
        for (int px = 0; px < 2; ++px)
            ob[(size_t)oc * kHW + px * 128] = acc[px][oc];
}

// ---------------------------------------------------------------------------
// FFT-256 radix-4 Stockham, 64-lane-per-FFT variant (row kernels).
// ---------------------------------------------------------------------------
__device__ __forceinline__ void fft256_stages(float2* A, float2* Bb, const float2* tw,
                                              int lane, float sgn)
{
    float2* src = A;
    float2* dst = Bb;
#pragma unroll
    for (int s = 0; s < 4; ++s) {
        int m = 1 << (2 * s);            // 1,4,16,64
        int r = lane & (m - 1);
        int mc = lane - r;               // m * floor(lane/m)
        __syncthreads();
        float2 x0 = src[lane];
        float2 x1 = src[lane + 128];
        float2 x2 = src[lane + 64];
        float2 x3 = src[lane + 192];
        float2 wa = tw[mc];
        float2 wb = tw[mc + 64];
        float2 wc = tw[2 * mc];
        float way = wa.y * sgn, wby = wb.y * sgn, wcy = wc.y * sgn;
        float e1x = x0.x + x1.x, e1y = x0.y + x1.y;
        float d1x = x0.x - x1.x, d1y = x0.y - x1.y;
        float o1x = wa.x * d1x - way * d1y, o1y = wa.x * d1y + way * d1x;
        float e2x = x2.x + x3.x, e2y = x2.y + x3.y;
        float d2x = x2.x - x3.x, d2y = x2.y - x3.y;
        float o2x = wb.x * d2x - wby * d2y, o2y = wb.x * d2y + wby * d2x;
        int base = r + 4 * mc;
        float2 y0; y0.x = e1x + e2x; y0.y = e1y + e2y;
        float ex = e1x - e2x, ey = e1y - e2y;
        float2 y2; y2.x = wc.x * ex - wcy * ey; y2.y = wc.x * ey + wcy * ex;
        float2 y1; y1.x = o1x + o2x; y1.y = o1y + o2y;
        float ox = o1x - o2x, oy = o1y - o2y;
        float2 y3; y3.x = wc.x * ox - wcy * oy; y3.y = wc.x * oy + wcy * ox;
        dst[base] = y0;
        dst[base + m] = y1;
        dst[base + 2 * m] = y2;
        dst[base + 3 * m] = y3;
        float2* t = src; src = dst; dst = t;
    }
    __syncthreads();
}

// 16-columns-per-block variant: 16 threads per FFT, 4 butterflies each.
// LDS layout [point][17] (float2), pad breaks bank alignment.
__device__ __forceinline__ void fft256_stages16(float2* A, float2* Bb, const float2* tw,
                                                int t, int c, float sgn)
{
    float2* src = A;
    float2* dst = Bb;
#pragma unroll
    for (int s = 0; s < 4; ++s) {
        int m = 1 << (2 * s);            // 1,4,16,64
        __syncthreads();
#pragma unroll
        for (int b = 0; b < 4; ++b) {
            int q = t + (b << 4);
            int r = q & (m - 1);
            int mc = q - r;
            float2 x0 = src[q * 17 + c];
            float2 x1 = src[(q + 128) * 17 + c];
            float2 x2 = src[(q + 64) * 17 + c];
            float2 x3 = src[(q + 192) * 17 + c];
            float2 wa = tw[mc];
            float2 wb = tw[mc + 64];
            float2 wc = tw[2 * mc];
            float way = wa.y * sgn, wby = wb.y * sgn, wcy = wc.y * sgn;
            float e1x = x0.x + x1.x, e1y = x0.y + x1.y;
            float d1x = x0.x - x1.x, d1y = x0.y - x1.y;
            float o1x = wa.x * d1x - way * d1y, o1y = wa.x * d1y + way * d1x;
            float e2x = x2.x + x3.x, e2y = x2.y + x3.y;
            float d2x = x2.x - x3.x, d2y = x2.y - x3.y;
            float o2x = wb.x * d2x - wby * d2y, o2y = wb.x * d2y + wby * d2x;
            int base = r + 4 * mc;
            float2 y0; y0.x = e1x + e2x; y0.y = e1y + e2y;
            float ex = e1x - e2x, ey = e1y - e2y;
            float2 y2; y2.x = wc.x * ex - wcy * ey; y2.y = wc.x * ey + wcy * ex;
            float2 y1; y1.x = o1x + o2x; y1.y = o1y + o2y;
            float ox = o1x - o2x, oy = o1y - o2y;
            float2 y3; y3.x = wc.x * ox - wcy * oy; y3.y = wc.x * oy + wcy * ox;
            dst[base * 17 + c] = y0;
            dst[(base + m) * 17 + c] = y1;
            dst[(base + 2 * m) * 17 + c] = y2;
            dst[(base + 3 * m) * 17 + c] = y3;
        }
        float2* tp = src; src = dst; dst = tp;
    }
    __syncthreads();
}

__device__ __forceinline__ void make_tw(float2* tw, int tid)
{
    if (tid < 128) {
        float ang = -kPI * (float)tid / 128.f;  // -2*pi*t/256
        float2 w; w.x = cosf(ang); w.y = sinf(ang);
        tw[tid] = w;
    }
}

// rows: real 256 -> 129 complex bins. 4 rows per block.
__global__ __launch_bounds__(256) void fft_rows_r2c(const float* __restrict__ in,
                                                    float2* __restrict__ out)
{
    __shared__ float2 A[4][256];
    __shared__ float2 Bb[4][256];
    __shared__ float2 tw[128];
    int tid = threadIdx.x;
    int sub = tid >> 6, lane = tid & 63;
    make_tw(tw, tid);
    size_t row = (size_t)blockIdx.x * 4 + sub;
    const float* rp = in + row * 256;
#pragma unroll
    for (int r = 0; r < 4; ++r) {
        int i = lane + 64 * r;
        float2 a; a.x = rp[i]; a.y = 0.f;
        A[sub][i] = a;
    }
    fft256_stages(A[sub], Bb[sub], tw, lane, 1.f);
    float2* op = out + row * kWF;
    op[lane] = A[sub][lane];
    op[lane + 64] = A[sub][lane + 64];
    if (lane == 0) op[128] = A[sub][128];
}

// cols forward: in-place complex FFT over H, 16 columns per block.
__global__ __launch_bounds__(256) void fft_cols16(float2* __restrict__ buf)
{
    __shared__ float2 A[256 * 17];
    __shared__ float2 Bb[256 * 17];
    __shared__ float2 tw[128];
    int tid = threadIdx.x;
    make_tw(tw, tid);
    int b = xcd_swizzle(blockIdx.x, gridDim.x);     // 2304 = 8 x 288
    int p = b / 9;
    int grp = b % 9;
    int col0 = grp * 16;
    int ncols = (col0 + 16 <= kWF) ? 16 : (kWF - col0);
    float2* base = buf + (size_t)p * kHWF + col0;
    for (int e = tid; e < 4096; e += 256) {
        int pp = e >> 4, cc = e & 15;
        if (cc < ncols) A[pp * 17 + cc] = base[(size_t)pp * kWF + cc];
    }
    int c = tid & 15, t = tid >> 4;
    fft256_stages16(A, Bb, tw, t, c, 1.f);
    for (int e = tid; e < 4096; e += 256) {
        int pp = e >> 4, cc = e & 15;
        if (cc < ncols) base[(size_t)pp * kWF + cc] = A[pp * 17 + cc];
    }
}

// inverse col FFT of (xf * real_mask), out-of-place, 16 cols per block.
__global__ __launch_bounds__(256) void ifft_cols_mask16(const float2* __restrict__ xf,
                                                        const float* __restrict__ spm,
                                                        float2* __restrict__ out)
{
    __shared__ float2 A[256 * 17];
    __shared__ float2 Bb[256 * 17];
    __shared__ float2 tw[128];
    int tid = threadIdx.x;
    make_tw(tw, tid);
    int b = xcd_swizzle(blockIdx.x, gridDim.x);
    int p = b / 9;
    int grp = b % 9;
    int col0 = grp * 16;
    int ncols = (col0 + 16 <= kWF) ? 16 : (kWF - col0);
    const float2* xb = xf + (size_t)p * kHWF + col0;
    const float* mb = spm + (size_t)p * kHWF + col0;
    for (int e = tid; e < 4096; e += 256) {
        int pp = e >> 4, cc = e & 15;
        if (cc < ncols) {
            float2 a = xb[(size_t)pp * kWF + cc];
            float m = mb[(size_t)pp * kWF + cc];
            a.x *= m; a.y *= m;
            A[pp * 17 + cc] = a;
        }
    }
    int c = tid & 15, t = tid >> 4;
    fft256_stages16(A, Bb, tw, t, c, -1.f);
    float2* ob = out + (size_t)p * kHWF + col0;
    for (int e = tid; e < 4096; e += 256) {
        int pp = e >> 4, cc = e & 15;
        if (cc < ncols) ob[(size_t)pp * kWF + cc] = A[pp * 17 + cc];
    }
}

// rows inverse: 129 complex (Hermitian-extended) -> 256 real, scaled 1/65536.
__global__ __launch_bounds__(256) void ifft_rows_c2r(const float2* __restrict__ in,
                                                     float* __restrict__ out)
{
    __shared__ float2 A[4][256];
    __shared__ float2 Bb[4][256];
    __shared__ float2 tw[128];
    int tid = threadIdx.x;
    int sub = tid >> 6, lane = tid & 63;
    make_tw(tw, tid);
    size_t row = (size_t)blockIdx.x * 4 + sub;
    const float2* ip = in + row * kWF;
#pragma unroll
    for (int r = 0; r < 4; ++r) {
        int k = lane + 64 * r;
        if (k <= 128) {
            A[sub][k] = ip[k];
        } else {
            float2 c = ip[256 - k];
            c.y = -c.y;
            A[sub][k] = c;
        }
    }
    fft256_stages(A[sub], Bb[sub], tw, lane, -1.f);
    float* op = out + row * 256;
#pragma unroll
    for (int r = 0; r < 4; ++r) {
        int k = lane + 64 * r;
        op[k] = A[sub][k].x * (1.f / 65536.f);
    }
}

// ---------------------------------------------------------------------------
// 1x1 conv on the frequency-domain planes. 1 px/thread (occupancy).
// ---------------------------------------------------------------------------
template <int CIN, int COUT, int ACT, bool CPLX>
__global__ __launch_bounds__(256) void conv1x1_kernel(
    const void* __restrict__ inv, const float* __restrict__ wg,
    const float* __restrict__ bias, float* __restrict__ out)
{
    constexpr int PL = kHWF;
    __shared__ __align__(16) float wl[COUT * CIN];
    __shared__ float bl[COUT];
    int tid = threadIdx.x;
    for (int e = tid; e < COUT * CIN; e += 256) wl[e] = wg[e];
    if (tid < COUT) bl[tid] = bias[tid];
    __syncthreads();

    int p0 = blockIdx.x * 256 + tid;   // grid 1032 x 256 = 264192 = N*PL exactly
    int n0 = p0 / PL, r0 = p0 % PL;

    float v0[CIN];
    if (CPLX) {
        const float2* in2 = (const float2*)inv;
#pragma unroll
        for (int c = 0; c < 32; ++c) {
            float2 a = in2[(size_t)(n0 * 32 + c) * PL + r0];
            v0[c] = a.x; v0[32 + c] = a.y;
        }
    } else {
        const float* inf_ = (const float*)inv;
#pragma unroll
        for (int c = 0; c < CIN; ++c) {
            v0[c] = inf_[(size_t)(n0 * CIN + c) * PL + r0];
        }
    }

#pragma unroll
    for (int oc = 0; oc < COUT; ++oc) {
        const float4* wr = reinterpret_cast<const float4*>(wl + oc * CIN);
        float a0 = bl[oc];
#pragma unroll
        for (int q = 0; q < CIN / 4; ++q) {
            float4 wv = wr[q];
            a0 += wv.x * v0[4*q] + wv.y * v0[4*q+1] + wv.z * v0[4*q+2] + wv.w * v0[4*q+3];
        }
        if (ACT == 1) a0 = fmaxf(a0, 0.f);
        if (ACT == 2) a0 = sigmoidf_(a0);
        out[(size_t)(n0 * COUT + oc) * PL + r0] = a0;
    }
}

// ---------------------------------------------------------------------------
// Fused: spm = sigmoid(w4 @ relu(w3 @ h2 + b3) + b4). 1 px/thread.
// ---------------------------------------------------------------------------
__global__ __launch_bounds__(256) void conv1x1_chain_kernel(
    const float* __restrict__ in, const float* __restrict__ w3,
    const float* __restrict__ b3, const float* __restrict__ w4,
    const float* __restrict__ b4, float* __restrict__ out)
{
    constexpr int PL = kHWF;
    __shared__ __align__(16) float wl3[64 * 64];
    __shared__ __align__(16) float wl4[32 * 64];
    __shared__ float bl3[64], bl4[32];
    int tid = threadIdx.x;
    for (int e = tid; e < 4096; e += 256) wl3[e] = w3[e];
    for (int e = tid; e < 2048; e += 256) wl4[e] = w4[e];
    if (tid < 64) bl3[tid] = b3[tid];
    if (tid < 32) bl4[tid] = b4[tid];
    __syncthreads();

    int p0 = blockIdx.x * 256 + tid;
    int n0 = p0 / PL, r0 = p0 % PL;

    float v0[64];
#pragma unroll
    for (int c = 0; c < 64; ++c) v0[c] = in[(size_t)(n0 * 64 + c) * PL + r0];

    float t0[64];
#pragma unroll
    for (int oc = 0; oc < 64; ++oc) {
        const float4* wr = reinterpret_cast<const float4*>(wl3 + oc * 64);
        float a0 = bl3[oc];
#pragma unroll
        for (int q = 0; q < 16; ++q) {
            float4 wv = wr[q];
            a0 += wv.x * v0[4*q] + wv.y * v0[4*q+1] + wv.z * v0[4*q+2] + wv.w * v0[4*q+3];
        }
        t0[oc] = fmaxf(a0, 0.f);
    }

#pragma unroll
    for (int oc = 0; oc < 32; ++oc) {
        const float4* wr = reinterpret_cast<const float4*>(wl4 + oc * 64);
        float a0 = bl4[oc];
#pragma unroll
        for (int q = 0; q < 16; ++q) {
            float4 wv = wr[q];
            a0 += wv.x * t0[4*q] + wv.y * t0[4*q+1] + wv.z * t0[4*q+2] + wv.w * t0[4*q+3];
        }
        out[(size_t)(n0 * 32 + oc) * PL + r0] = sigmoidf_(a0);
    }
}

// ---------------------------------------------------------------------------
// Final: GLU with exact gelu, 1x1 conv 16->32, bias, + residual input_flow.
// ---------------------------------------------------------------------------
__global__ __launch_bounds__(256) void final_kernel(
    const float* __restrict__ g, const float* __restrict__ flow,
    const float* __restrict__ wg, const float* __restrict__ bias,
    float* __restrict__ out)
{
    __shared__ __align__(16) float wl[32 * 16];
    __shared__ float bl[32];
    int tid = threadIdx.x;
    for (int e = tid; e < 512; e += 256) wl[e] = wg[e];
    if (tid < 32) bl[tid] = bias[tid];
    __syncthreads();

    int p = blockIdx.x * 256 + tid;
    int n = p >> 16;
    int rem = p & 65535;
    const float* gb = g + (size_t)n * 32 * kHW + rem;

    float v[16];
#pragma unroll
    for (int c = 0; c < 16; ++c) {
        float a = gb[(size_t)c * kHW];
        float b = gb[(size_t)(16 + c) * kHW];
        float ge = 0.5f * b * (1.f + erff(b * 0.70710678118654752f));
        v[c] = a * ge;
    }

    const float* fb = flow + (size_t)n * 32 * kHW + rem;
    float* ob = out + (size_t)n * 32 * kHW + rem;
#pragma unroll
    for (int oc = 0; oc < 32; ++oc) {
        const float4* wr = reinterpret_cast<const float4*>(wl + oc * 16);
        float acc = bl[oc];
#pragma unroll
        for (int q = 0; q < 4; ++q) {
            float4 wv = wr[q];
            acc += wv.x * v[4*q] + wv.y * v[4*q+1] + wv.z * v[4*q+2] + wv.w * v[4*q+3];
        }
        ob[(size_t)oc * kHW] = acc + fb[(size_t)oc * kHW];
    }
}

// ---------------------------------------------------------------------------
// Buffer plan (3 ws slots of 16,908,288 floats + d_out):
//   A: t1 -> offset -> xf(complex, live 7..13) -> g
//   B: t2 -> mask -> dcf -> h2 -> ycol
//   C: t3 -> dc -> h1 -> spm -> x_irfft
//   d_out: x (steps 3..7) -> final output
// ---------------------------------------------------------------------------
extern "C" void kernel_launch(void* const* d_in, const int* in_sizes, int n_in,
                              void* d_out, int out_size, void* d_ws, size_t ws_size,
                              hipStream_t stream)
{
    (void)in_sizes; (void)n_in; (void)out_size; (void)ws_size;

    const float* input_flow  = (const float*)d_in[0];
    const float* input_event = (const float*)d_in[1];
    const float* ln_flow_g   = (const float*)d_in[2];
    const float* ln_flow_b   = (const float*)d_in[3];
    const float* ln_event_g  = (const float*)d_in[4];
    const float* ln_event_b  = (const float*)d_in[5];
    const float* ff_w1 = (const float*)d_in[6];
    const float* ff_b1 = (const float*)d_in[7];
    const float* ff_w2 = (const float*)d_in[8];
    const float* ff_b2 = (const float*)d_in[9];
    const float* fo_w1 = (const float*)d_in[10];
    const float* fo_b1 = (const float*)d_in[11];
    const float* fo_w2 = (const float*)d_in[12];
    const float* fo_b2 = (const float*)d_in[13];
    const float* fm_w1 = (const float*)d_in[14];
    const float* fm_b1 = (const float*)d_in[15];
    const float* fm_w2 = (const float*)d_in[16];
    const float* fm_b2 = (const float*)d_in[17];
    const float* dc_weight = (const float*)d_in[18];
    const float* sf_w1 = (const float*)d_in[19];
    const float* sf_b1 = (const float*)d_in[20];
    const float* sf_w2 = (const float*)d_in[21];
    const float* sf_b2 = (const float*)d_in[22];
    const float* sf_w3 = (const float*)d_in[23];
    const float* sf_b3 = (const float*)d_in[24];
    const float* sf_w4 = (const float*)d_in[25];
    const float* sf_b4 = (const float*)d_in[26];
    const float* fl_w1 = (const float*)d_in[27];
    const float* fl_b1 = (const float*)d_in[28];
    const float* fl_w2 = (const float*)d_in[29];
    const float* fl_b2 = (const float*)d_in[30];
    float* out = (float*)d_out;

    const size_t S = (size_t)16908288;
    float* A = (float*)d_ws;
    float* B = A + S;
    float* Cs = B + S;
    float* X = out;   // x lives in d_out between steps 3 and 7

    // 1) t1 = relu(ff_w1 @ LN(flow))              -> A
    lnmv_kernel<false><<<2048, 256, 0, stream>>>(input_flow, ln_flow_g, ln_flow_b,
                                                 ff_w1, ff_b1, A,
                                                 nullptr, nullptr, nullptr);
    // 2) t2 = relu(fo_w1 @ LN(event)) -> B ; t3 = relu(fm_w1 @ LN(event)) -> C
    lnmv_kernel<true><<<2048, 256, 0, stream>>>(input_event, ln_event_g, ln_event_b,
                                                fo_w1, fo_b1, B,
                                                fm_w1, fm_b1, Cs);
    // 3) x = dw3x3(t1) + ff_b2                    -> X (d_out)
    dw3x3_kernel<<<65536, 256, 0, stream>>>(A, ff_w2, ff_b2, X, 32, 256, 256, 16777216);
    // 4) offset = conv3x3(t2)                     -> A
    conv3x3_kernel<18, 20, 0><<<512, 256, 0, stream>>>(B, fo_w2, fo_b2, A);
    // 5) mask = sigmoid(conv3x3(t3))              -> B
    conv3x3_kernel<9, 12, 2><<<512, 256, 0, stream>>>(Cs, fm_w2, fm_b2, B);
    // 6) dc = deform(x, offset, mask)             -> C
    deform_kernel<<<1024, 256, 0, stream>>>(X, A, B, dc_weight, Cs);
    // 7) xf = rfft2(x)                            -> A (float2)
    fft_rows_r2c<<<16384, 256, 0, stream>>>(X, (float2*)A);
    fft_cols16<<<2304, 256, 0, stream>>>((float2*)A);
    // 8) dcf = rfft2(dc)                          -> B (float2)
    fft_rows_r2c<<<16384, 256, 0, stream>>>(Cs, (float2*)B);
    fft_cols16<<<2304, 256, 0, stream>>>((float2*)B);
    // 9) h1 = sf_w1 @ [re(dcf); im(dcf)] + b      -> C
    conv1x1_kernel<64, 64, 0, true><<<1032, 256, 0, stream>>>((const void*)B, sf_w1, sf_b1, Cs);
    // 10) h2 = dw3x3(h1) + sf_b2                  -> B
    dw3x3_kernel<<<66048, 256, 0, stream>>>(Cs, sf_w2, sf_b2, B, 64, 256, 129, 16908288);
    // 11+12) spm = sigmoid(w4 @ relu(w3 @ h2))    -> C
    conv1x1_chain_kernel<<<1032, 256, 0, stream>>>(B, sf_w3, sf_b3, sf_w4, sf_b4, Cs);
    // 13) ycol = ifft_cols(xf * spm)              -> B (float2)
    ifft_cols_mask16<<<2304, 256, 0, stream>>>((const float2*)A, Cs, (float2*)B);
    // 14) x_irfft = ifft_rows_c2r(ycol)           -> C
    ifft_rows_c2r<<<16384, 256, 0, stream>>>((const float2*)B, Cs);
    // 15) g = dw3x3(x_irfft) + fl_b1              -> A
    dw3x3_kernel<<<65536, 256, 0, stream>>>(Cs, fl_w1, fl_b1, A, 32, 256, 256, 16777216);
    // 16) out = fl_w2 @ (a * gelu(b)) + fl_b2 + input_flow  (overwrites X)
    final_kernel<<<2048, 256, 0, stream>>>(A, input_flow, fl_w2, fl_b2, out);
}